// Round 3
// baseline (204.421 us; speedup 1.0000x reference)
//
#include <hip/hip_runtime.h>

#define D_DIM    1024
#define PER_LANE 16   // D / 64
#define NLAYER   2
#define NPAIR    8    // ent pairs per lane
#define WPB      4    // waves per block (blockDim = 256)
#define ROWS_PW  8    // rows per wave

// XOR swizzle on 16B-chunk index: involution; with pre-swizzled global source
// the LDS image is swizzled so segment reads/writes AND coalesced reads are
// all bank-uniform (derived: groups (4(l&1)+r)^((l>>1)&7) and (l&7)^(l>>3)).
__device__ __forceinline__ int swz(int c) { return c ^ ((c >> 3) & 7); }

// ---------------- kernel 1: angle tables (once per call) ----------------
// tab layout (floats): [0]=cos_local[2][1024], [2048]=sin_local[2][1024],
//                      [4096]=cos_ent[2][512], [5120]=sin_ent[2][512]
__global__ void angles_kernel(const float* __restrict__ la,
                              const float* __restrict__ ea,
                              float* __restrict__ tab) {
    int t  = blockIdx.x * blockDim.x + threadIdx.x;
    int nt = gridDim.x * blockDim.x;
    for (int i = t; i < NLAYER * D_DIM; i += nt) {
        float s, c; sincosf(la[i], &s, &c);
        tab[i] = c; tab[2048 + i] = s;
    }
    for (int i = t; i < NLAYER * (D_DIM / 2); i += nt) {
        float s, c; sincosf(ea[i], &s, &c);
        tab[4096 + i] = c; tab[5120 + i] = s;
    }
}

// ---------------- kernel 2: main ----------------
__global__ __launch_bounds__(256, 4) void qent_kernel(
        const float* __restrict__ x,
        const float* __restrict__ tab,
        float* __restrict__ out, int B)
{
    const int lane = threadIdx.x & 63;
    const int wid  = threadIdx.x >> 6;
    const int gwave = blockIdx.x * WPB + wid;

    __shared__ float4 buf[WPB][2][256];            // 32 KB: dbuf transpose
    __shared__ float  lds_ce[NLAYER][NPAIR][64];   // 4 KB
    __shared__ float  lds_se[NLAYER][NPAIR][64];   // 4 KB

    // Stage ent coefficients [L][m][lane] (conflict-free reads & writes).
    for (int t = threadIdx.x; t < NLAYER * 512; t += 256) {
        int L = t >> 9, p = t & 511;
        int m = p >> 6, ln = p & 63;
        lds_ce[L][m][ln] = tab[4096 + L * 512 + ln * 8 + m];
        lds_se[L][m][ln] = tab[5120 + L * 512 + ln * 8 + m];
    }
    __syncthreads();

    // Local-rotation coefficients straight to registers (coalesced float4).
    float cl[NLAYER][PER_LANE], sl[NLAYER][PER_LANE];
    #pragma unroll
    for (int L = 0; L < NLAYER; ++L) {
        const float4* cp = reinterpret_cast<const float4*>(tab + L * D_DIM + lane * PER_LANE);
        const float4* sp = reinterpret_cast<const float4*>(tab + 2048 + L * D_DIM + lane * PER_LANE);
        #pragma unroll
        for (int q = 0; q < 4; ++q) {
            float4 c4 = cp[q], s4 = sp[q];
            cl[L][4*q+0] = c4.x; cl[L][4*q+1] = c4.y; cl[L][4*q+2] = c4.z; cl[L][4*q+3] = c4.w;
            sl[L][4*q+0] = s4.x; sl[L][4*q+1] = s4.y; sl[L][4*q+2] = s4.z; sl[L][4*q+3] = s4.w;
        }
    }

    // Direct-to-LDS stage with pre-swizzled global source (HK s09 pattern):
    // LDS chunk q*64+l receives row chunk q*64+(l^(l>>3))  =>  image is swz'd.
    const int l2 = lane ^ (lane >> 3);
    auto stage = [&](int b, int row) {
        const float* src = x + (size_t)row * D_DIM;
        #pragma unroll
        for (int q = 0; q < 4; ++q) {
            const float* gp = src + q * 256 + l2 * 4;
            void* lp = (void*)&buf[wid][b][q * 64];
            __builtin_amdgcn_global_load_lds(
                (const __attribute__((address_space(1))) void*)gp,
                (__attribute__((address_space(3))) void*)lp, 16, 0, 0);
        }
    };

    const int row0 = gwave * ROWS_PW;
    stage(0, row0);

    #pragma unroll
    for (int it = 0; it < ROWS_PW; ++it) {
        const int cur = it & 1;
        const int row = row0 + it;

        // Current buffer's 4 direct-to-LDS loads are the oldest outstanding
        // VMEM ops; drain everything (stores from it-1 are ~1 phase old).
        asm volatile("s_waitcnt vmcnt(0)" ::: "memory");

        // Prefetch next row while we compute this one.
        if (it + 1 < ROWS_PW) stage(cur ^ 1, row + 1);

        // ---- segment read: lane l owns columns [16l, 16l+16) ----
        float v[PER_LANE];
        #pragma unroll
        for (int r = 0; r < 4; ++r) {
            float4 t = buf[wid][cur][swz(4 * lane + r)];
            v[4*r+0] = t.x; v[4*r+1] = t.y; v[4*r+2] = t.z; v[4*r+3] = t.w;
        }

        #pragma unroll
        for (int L = 0; L < NLAYER; ++L) {
            // ---------- local chain: u_{i+1} = s_i u_i + c_i v_{i+1} ----------
            float vnf = __shfl_down(v[0], 1);  // lane l+1's ORIGINAL v[0]

            // pass 1: this lane's composed affine map (A, B)
            float A = 1.f, Bv = 0.f;
            #pragma unroll
            for (int k = 0; k < PER_LANE; ++k) {
                float vn = (k < PER_LANE - 1) ? v[k + 1] : vnf;
                Bv = sl[L][k] * Bv + cl[L][k] * vn;
                A  = sl[L][k] * A;
            }

            // inclusive Hillis-Steele affine scan across 64 lanes
            float Ai = A, Bi = Bv;
            #pragma unroll
            for (int dd = 1; dd < 64; dd <<= 1) {
                float Au = __shfl_up(Ai, dd);
                float Bu = __shfl_up(Bi, dd);
                if (lane >= dd) {
                    Bi = Ai * Bu + Bi;
                    Ai = Ai * Au;
                }
            }
            float Ax  = __shfl_up(Ai, 1);
            float Bx  = __shfl_up(Bi, 1);
            float v0b = __shfl(v[0], 0);
            float u   = (lane == 0) ? v[0] : (Ax * v0b + Bx);

            // replay: finals f_i = c_i u_i - s_i v_{i+1}
            #pragma unroll
            for (int k = 0; k < PER_LANE - 1; ++k) {
                float vn = v[k + 1];
                float f  = cl[L][k] * u - sl[L][k] * vn;
                u        = sl[L][k] * u + cl[L][k] * vn;
                v[k] = f;
            }
            // wrap step i = D-1 uses a0 = provisional f_0 (lane 0)
            float a0   = __shfl(v[0], 0);
            float vn15 = (lane == 63) ? a0 : vnf;
            float f15  = cl[L][PER_LANE-1] * u - sl[L][PER_LANE-1] * vn15;
            float un   = sl[L][PER_LANE-1] * u + cl[L][PER_LANE-1] * vn15;
            v[PER_LANE-1] = f15;
            float f0new = __shfl(un, 63);
            if (lane == 0) v[0] = f0new;

            // ---------- ent layer: disjoint pairs, lane-local ----------
            #pragma unroll
            for (int m = 0; m < NPAIR; ++m) {
                float cem = lds_ce[L][m][lane];
                float sem = lds_se[L][m][lane];
                float x0 = v[2*m], x1 = v[2*m+1];
                v[2*m]   = cem * x0 - sem * x1;
                v[2*m+1] = sem * x0 + cem * x1;
            }
        }

        // ---- segment write back (swizzled), then coalesced store ----
        #pragma unroll
        for (int r = 0; r < 4; ++r) {
            float4 t;
            t.x = v[4*r+0]; t.y = v[4*r+1]; t.z = v[4*r+2]; t.w = v[4*r+3];
            buf[wid][cur][swz(4 * lane + r)] = t;
        }
        float4* op = reinterpret_cast<float4*>(out + (size_t)row * D_DIM);
        #pragma unroll
        for (int q = 0; q < 4; ++q) {
            float4 t = buf[wid][cur][swz(q * 64 + lane)];
            op[q * 64 + lane] = t;
        }
    }
}

extern "C" void kernel_launch(void* const* d_in, const int* in_sizes, int n_in,
                              void* d_out, int out_size, void* d_ws, size_t ws_size,
                              hipStream_t stream) {
    const float* x  = (const float*)d_in[0];
    const float* la = (const float*)d_in[1];
    const float* ea = (const float*)d_in[2];
    float* out = (float*)d_out;
    float* tab = (float*)d_ws;               // 6144 floats = 24 KB
    int B = in_sizes[0] / D_DIM;             // 32768

    angles_kernel<<<8, 256, 0, stream>>>(la, ea, tab);
    int blocks = B / (WPB * ROWS_PW);        // 1024
    qent_kernel<<<blocks, 256, 0, stream>>>(x, tab, out, B);
}

// Round 4
// 125.835 us; speedup vs baseline: 1.6245x; 1.6245x over previous
//
#include <hip/hip_runtime.h>

#define D_DIM    1024
#define PER_LANE 16   // D / 64
#define NLAYER   2
#define NPAIR    8    // ent pairs per lane
#define WPB      4    // waves per block (blockDim = 256)

// XOR swizzle over 16B chunk index: bijective involution; makes both the
// coalesced phase (chunks q*64+l) and the segment phase (chunks 4l+r)
// uniform across the 8 LDS bank-groups.
__device__ __forceinline__ int swz(int c) { return c ^ ((c >> 3) & 7); }

// ---------------- kernel 1: angle tables (once per call) ----------------
// tab layout (floats): [0]=cos_local[2][1024], [2048]=sin_local[2][1024],
//                      [4096]=cos_ent[2][512], [5120]=sin_ent[2][512]
__global__ void angles_kernel(const float* __restrict__ la,
                              const float* __restrict__ ea,
                              float* __restrict__ tab) {
    int t  = blockIdx.x * blockDim.x + threadIdx.x;
    int nt = gridDim.x * blockDim.x;
    for (int i = t; i < NLAYER * D_DIM; i += nt) {
        float s, c; sincosf(la[i], &s, &c);
        tab[i] = c; tab[2048 + i] = s;
    }
    for (int i = t; i < NLAYER * (D_DIM / 2); i += nt) {
        float s, c; sincosf(ea[i], &s, &c);
        tab[4096 + i] = c; tab[5120 + i] = s;
    }
}

// ---------------- kernel 2: main ----------------
__global__ __launch_bounds__(256) void qent_kernel(
        const float* __restrict__ x,
        const float* __restrict__ tab,
        float* __restrict__ out, int B)
{
    const int lane  = threadIdx.x & 63;
    const int wid   = threadIdx.x >> 6;
    const int gwave = blockIdx.x * WPB + wid;
    const int nwave = gridDim.x * WPB;

    __shared__ float4 tb[WPB][256];                // 16 KB transpose buffer
    __shared__ float  lds_ce[NLAYER][NPAIR][64];   // 4 KB
    __shared__ float  lds_se[NLAYER][NPAIR][64];   // 4 KB

    // Ent coefficients -> LDS [L][m][lane]: writes lane-consecutive
    // (conflict-free), reads lane-consecutive (conflict-free).
    for (int t = threadIdx.x; t < NLAYER * 512; t += 256) {
        int L = t >> 9, p = t & 511;
        int m = p >> 6, ln = p & 63;
        lds_ce[L][m][ln] = tab[4096 + L * 512 + ln * 8 + m];
        lds_se[L][m][ln] = tab[5120 + L * 512 + ln * 8 + m];
    }
    __syncthreads();

    // Local-rotation coefficients straight to registers (coalesced float4).
    float cl[NLAYER][PER_LANE], sl[NLAYER][PER_LANE];
    #pragma unroll
    for (int L = 0; L < NLAYER; ++L) {
        const float4* cp = reinterpret_cast<const float4*>(tab + L * D_DIM + lane * PER_LANE);
        const float4* sp = reinterpret_cast<const float4*>(tab + 2048 + L * D_DIM + lane * PER_LANE);
        #pragma unroll
        for (int q = 0; q < 4; ++q) {
            float4 c4 = cp[q], s4 = sp[q];
            cl[L][4*q+0] = c4.x; cl[L][4*q+1] = c4.y; cl[L][4*q+2] = c4.z; cl[L][4*q+3] = c4.w;
            sl[L][4*q+0] = s4.x; sl[L][4*q+1] = s4.y; sl[L][4*q+2] = s4.z; sl[L][4*q+3] = s4.w;
        }
    }

    // ---- grid-stride loop with depth-1 register prefetch ----
    int row = gwave;
    float4 cur[4];
    if (row < B) {
        const float4* rp = reinterpret_cast<const float4*>(x + (size_t)row * D_DIM);
        #pragma unroll
        for (int q = 0; q < 4; ++q) cur[q] = rp[q * 64 + lane];
    }

    for (; row < B; row += nwave) {
        // Issue next row's loads NOW; latency hides under this row's compute.
        const int nrow = row + nwave;
        float4 nxt[4];
        if (nrow < B) {
            const float4* rp = reinterpret_cast<const float4*>(x + (size_t)nrow * D_DIM);
            #pragma unroll
            for (int q = 0; q < 4; ++q) nxt[q] = rp[q * 64 + lane];
        }

        // ---- coalesced image -> swizzled LDS ----
        #pragma unroll
        for (int q = 0; q < 4; ++q) tb[wid][swz(q * 64 + lane)] = cur[q];

        // ---- segment read: lane l owns columns [16l, 16l+16) ----
        float v[PER_LANE];
        #pragma unroll
        for (int r = 0; r < 4; ++r) {
            float4 t = tb[wid][swz(4 * lane + r)];
            v[4*r+0] = t.x; v[4*r+1] = t.y; v[4*r+2] = t.z; v[4*r+3] = t.w;
        }

        #pragma unroll
        for (int L = 0; L < NLAYER; ++L) {
            // ---------- local chain: u_{i+1} = s_i u_i + c_i v_{i+1} ----------
            float vnf = __shfl_down(v[0], 1);  // lane l+1's ORIGINAL v[0]

            // pass 1: this lane's composed affine map (A, B)
            float A = 1.f, Bv = 0.f;
            #pragma unroll
            for (int k = 0; k < PER_LANE; ++k) {
                float vn = (k < PER_LANE - 1) ? v[k + 1] : vnf;
                Bv = sl[L][k] * Bv + cl[L][k] * vn;
                A  = sl[L][k] * A;
            }

            // inclusive Hillis-Steele affine scan across 64 lanes
            float Ai = A, Bi = Bv;
            #pragma unroll
            for (int dd = 1; dd < 64; dd <<= 1) {
                float Au = __shfl_up(Ai, dd);
                float Bu = __shfl_up(Bi, dd);
                if (lane >= dd) {
                    Bi = Ai * Bu + Bi;
                    Ai = Ai * Au;
                }
            }
            float Ax  = __shfl_up(Ai, 1);
            float Bx  = __shfl_up(Bi, 1);
            float v0b = __shfl(v[0], 0);
            float u   = (lane == 0) ? v[0] : (Ax * v0b + Bx);

            // replay: finals f_i = c_i u_i - s_i v_{i+1}
            #pragma unroll
            for (int k = 0; k < PER_LANE - 1; ++k) {
                float vn = v[k + 1];
                float f  = cl[L][k] * u - sl[L][k] * vn;
                u        = sl[L][k] * u + cl[L][k] * vn;
                v[k] = f;
            }
            // wrap step i = D-1 uses a0 = provisional f_0 (lane 0)
            float a0   = __shfl(v[0], 0);
            float vn15 = (lane == 63) ? a0 : vnf;
            float f15  = cl[L][PER_LANE-1] * u - sl[L][PER_LANE-1] * vn15;
            float un   = sl[L][PER_LANE-1] * u + cl[L][PER_LANE-1] * vn15;
            v[PER_LANE-1] = f15;
            float f0new = __shfl(un, 63);
            if (lane == 0) v[0] = f0new;

            // ---------- ent layer: disjoint pairs, lane-local ----------
            #pragma unroll
            for (int m = 0; m < NPAIR; ++m) {
                float cem = lds_ce[L][m][lane];
                float sem = lds_se[L][m][lane];
                float x0 = v[2*m], x1 = v[2*m+1];
                v[2*m]   = cem * x0 - sem * x1;
                v[2*m+1] = sem * x0 + cem * x1;
            }
        }

        // ---- segment write back (swizzled), then coalesced store ----
        #pragma unroll
        for (int r = 0; r < 4; ++r) {
            float4 t;
            t.x = v[4*r+0]; t.y = v[4*r+1]; t.z = v[4*r+2]; t.w = v[4*r+3];
            tb[wid][swz(4 * lane + r)] = t;
        }
        float4* op = reinterpret_cast<float4*>(out + (size_t)row * D_DIM);
        float4 st[4];
        #pragma unroll
        for (int q = 0; q < 4; ++q) st[q] = tb[wid][swz(q * 64 + lane)];
        #pragma unroll
        for (int q = 0; q < 4; ++q) op[q * 64 + lane] = st[q];

        #pragma unroll
        for (int q = 0; q < 4; ++q) cur[q] = nxt[q];
    }
}

extern "C" void kernel_launch(void* const* d_in, const int* in_sizes, int n_in,
                              void* d_out, int out_size, void* d_ws, size_t ws_size,
                              hipStream_t stream) {
    const float* x  = (const float*)d_in[0];
    const float* la = (const float*)d_in[1];
    const float* ea = (const float*)d_in[2];
    float* out = (float*)d_out;
    float* tab = (float*)d_ws;               // 6144 floats = 24 KB
    int B = in_sizes[0] / D_DIM;             // 32768

    angles_kernel<<<8, 256, 0, stream>>>(la, ea, tab);
    qent_kernel<<<2048, 256, 0, stream>>>(x, tab, out, B);
}

// Round 5
// 62.136 us; speedup vs baseline: 3.2899x; 2.0251x over previous
//
#include <hip/hip_runtime.h>

#define D_DIM    1024
#define PER_LANE 16   // D / 64
#define NLAYER   2
#define NPAIR    8    // ent pairs per lane
#define WPB      4    // waves per block (blockDim = 256)

// XOR swizzle over 16B chunk index: bijective involution; makes the coalesced
// phase (chunks q*64+l) and the segment phase (chunks 4l+r) bank-uniform.
__device__ __forceinline__ int swz(int c) { return c ^ ((c >> 3) & 7); }

// ---------------- kernel 1: angle tables (once per call) ----------------
// tab floats: [0]=cos_local[2][1024], [2048]=sin_local[2][1024],
//             [4096]=cos_ent[2][512], [5120]=sin_ent[2][512]
__global__ void angles_kernel(const float* __restrict__ la,
                              const float* __restrict__ ea,
                              float* __restrict__ tab) {
    int t  = blockIdx.x * blockDim.x + threadIdx.x;
    int nt = gridDim.x * blockDim.x;
    for (int i = t; i < NLAYER * D_DIM; i += nt) {
        float s, c; sincosf(la[i], &s, &c);
        tab[i] = c; tab[2048 + i] = s;
    }
    for (int i = t; i < NLAYER * (D_DIM / 2); i += nt) {
        float s, c; sincosf(ea[i], &s, &c);
        tab[4096 + i] = c; tab[5120 + i] = s;
    }
}

// ---------------- kernel 2: main ----------------
__global__ __launch_bounds__(256) void qent_kernel(
        const float* __restrict__ x,
        const float* __restrict__ tab,
        float* __restrict__ out, int B)
{
    const int lane  = threadIdx.x & 63;
    const int wid   = threadIdx.x >> 6;
    const int gwave = blockIdx.x * WPB + wid;
    const int nwave = gridDim.x * WPB;

    __shared__ float4 tb[WPB][2][256];             // 32 KB: per-wave dbuf
    __shared__ float  lds_ce[NLAYER][NPAIR][64];   // 4 KB
    __shared__ float  lds_se[NLAYER][NPAIR][64];   // 4 KB

    // Ent coefficients -> LDS [L][m][lane] (conflict-free on read).
    for (int t = threadIdx.x; t < NLAYER * 512; t += 256) {
        int L = t >> 9, p = t & 511;
        int m = p >> 6, ln = p & 63;
        lds_ce[L][m][ln] = tab[4096 + L * 512 + ln * 8 + m];
        lds_se[L][m][ln] = tab[5120 + L * 512 + ln * 8 + m];
    }
    __syncthreads();

    // Local-rotation coefficients in registers (coalesced float4 loads).
    float cl[NLAYER][PER_LANE], sl[NLAYER][PER_LANE];
    #pragma unroll
    for (int L = 0; L < NLAYER; ++L) {
        const float4* cp = reinterpret_cast<const float4*>(tab + L * D_DIM + lane * PER_LANE);
        const float4* sp = reinterpret_cast<const float4*>(tab + 2048 + L * D_DIM + lane * PER_LANE);
        #pragma unroll
        for (int q = 0; q < 4; ++q) {
            float4 c4 = cp[q], s4 = sp[q];
            cl[L][4*q+0] = c4.x; cl[L][4*q+1] = c4.y; cl[L][4*q+2] = c4.z; cl[L][4*q+3] = c4.w;
            sl[L][4*q+0] = s4.x; sl[L][4*q+1] = s4.y; sl[L][4*q+2] = s4.z; sl[L][4*q+3] = s4.w;
        }
    }

    // Direct-to-LDS stage, pre-swizzled global source: LDS chunk q*64+l
    // receives global chunk q*64 + (l ^ (l>>3))  =>  LDS image is swz'd.
    const int l2 = lane ^ (lane >> 3);
    auto stage = [&](int b, int row) {
        const float* src = x + (size_t)row * D_DIM;
        #pragma unroll
        for (int q = 0; q < 4; ++q) {
            __builtin_amdgcn_global_load_lds(
                (const __attribute__((address_space(1))) void*)(src + q * 256 + l2 * 4),
                (__attribute__((address_space(3))) void*)&tb[wid][b][q * 64],
                16, 0, 0);
        }
    };

    stage(0, gwave);

    int it = 0;
    for (int row = gwave; row < B; row += nwave, ++it) {
        const int cur  = it & 1;
        const int nrow = row + nwave;

        // Issue next stage FIRST, then counted wait: the 4 newest outstanding
        // VMEM ops are stage(next); vmcnt(4) drains stage(cur) + old stores
        // while next row's loads stay in flight under this row's compute.
        if (nrow < B) {
            stage(cur ^ 1, nrow);
            asm volatile("s_waitcnt vmcnt(4)" ::: "memory");
        } else {
            asm volatile("s_waitcnt vmcnt(0)" ::: "memory");
        }

        // ---- segment read: lane l owns columns [16l, 16l+16) ----
        float v[PER_LANE];
        #pragma unroll
        for (int r = 0; r < 4; ++r) {
            float4 t = tb[wid][cur][swz(4 * lane + r)];
            v[4*r+0] = t.x; v[4*r+1] = t.y; v[4*r+2] = t.z; v[4*r+3] = t.w;
        }

        #pragma unroll
        for (int L = 0; L < NLAYER; ++L) {
            // ---------- local chain: u_{i+1} = s_i u_i + c_i v_{i+1} ----------
            float vnf = __shfl_down(v[0], 1);  // lane l+1's ORIGINAL v[0]

            // pass 1: this lane's composed affine map (A, B)
            float A = 1.f, Bv = 0.f;
            #pragma unroll
            for (int k = 0; k < PER_LANE; ++k) {
                float vn = (k < PER_LANE - 1) ? v[k + 1] : vnf;
                Bv = sl[L][k] * Bv + cl[L][k] * vn;
                A  = sl[L][k] * A;
            }

            // inclusive Hillis-Steele affine scan across 64 lanes
            float Ai = A, Bi = Bv;
            #pragma unroll
            for (int dd = 1; dd < 64; dd <<= 1) {
                float Au = __shfl_up(Ai, dd);
                float Bu = __shfl_up(Bi, dd);
                if (lane >= dd) {
                    Bi = Ai * Bu + Bi;
                    Ai = Ai * Au;
                }
            }
            float Ax  = __shfl_up(Ai, 1);
            float Bx  = __shfl_up(Bi, 1);
            float v0b = __shfl(v[0], 0);
            float u   = (lane == 0) ? v[0] : (Ax * v0b + Bx);

            // replay: finals f_i = c_i u_i - s_i v_{i+1}
            #pragma unroll
            for (int k = 0; k < PER_LANE - 1; ++k) {
                float vn = v[k + 1];
                float f  = cl[L][k] * u - sl[L][k] * vn;
                u        = sl[L][k] * u + cl[L][k] * vn;
                v[k] = f;
            }
            // wrap step i = D-1 uses a0 = provisional f_0 (lane 0)
            float a0   = __shfl(v[0], 0);
            float vn15 = (lane == 63) ? a0 : vnf;
            float f15  = cl[L][PER_LANE-1] * u - sl[L][PER_LANE-1] * vn15;
            float un   = sl[L][PER_LANE-1] * u + cl[L][PER_LANE-1] * vn15;
            v[PER_LANE-1] = f15;
            float f0new = __shfl(un, 63);
            if (lane == 0) v[0] = f0new;

            // ---------- ent layer: disjoint pairs, lane-local ----------
            #pragma unroll
            for (int m = 0; m < NPAIR; ++m) {
                float cem = lds_ce[L][m][lane];
                float sem = lds_se[L][m][lane];
                float x0 = v[2*m], x1 = v[2*m+1];
                v[2*m]   = cem * x0 - sem * x1;
                v[2*m+1] = sem * x0 + cem * x1;
            }
        }

        // ---- segment write back (swizzled), then coalesced store ----
        #pragma unroll
        for (int r = 0; r < 4; ++r) {
            float4 t;
            t.x = v[4*r+0]; t.y = v[4*r+1]; t.z = v[4*r+2]; t.w = v[4*r+3];
            tb[wid][cur][swz(4 * lane + r)] = t;
        }
        float4* op = reinterpret_cast<float4*>(out + (size_t)row * D_DIM);
        #pragma unroll
        for (int q = 0; q < 4; ++q) {
            float4 t = tb[wid][cur][swz(q * 64 + lane)];
            op[q * 64 + lane] = t;
        }
    }
}

extern "C" void kernel_launch(void* const* d_in, const int* in_sizes, int n_in,
                              void* d_out, int out_size, void* d_ws, size_t ws_size,
                              hipStream_t stream) {
    const float* x  = (const float*)d_in[0];
    const float* la = (const float*)d_in[1];
    const float* ea = (const float*)d_in[2];
    float* out = (float*)d_out;
    float* tab = (float*)d_ws;               // 6144 floats = 24 KB
    int B = in_sizes[0] / D_DIM;             // 32768

    angles_kernel<<<8, 256, 0, stream>>>(la, ea, tab);
    // 1024 blocks x 4 waves: all co-resident (4 blocks/CU @ 40KB LDS),
    // 8 rows per wave -> 7/8 iterations in prefetched steady state.
    qent_kernel<<<1024, 256, 0, stream>>>(x, tab, out, B);
}

// Round 6
// 57.779 us; speedup vs baseline: 3.5380x; 1.0754x over previous
//
#include <hip/hip_runtime.h>

#define D_DIM    1024
#define PER_LANE 16   // D / 64
#define NLAYER   2
#define NPAIR    8    // ent pairs per lane
#define WPB      4    // waves per block (blockDim = 256)

// XOR swizzle over 16B chunk index: bijective involution; makes the coalesced
// phase (chunks q*64+l) and the segment phase (chunks 4l+r) bank-uniform.
__device__ __forceinline__ int swz(int c) { return c ^ ((c >> 3) & 7); }

// DPP move with explicit old-value for invalid/masked lanes (affine identity).
template<int CTRL, int RMASK>
__device__ __forceinline__ float dpp_mov(float src, float oldv) {
    return __int_as_float(__builtin_amdgcn_update_dpp(
        __float_as_int(oldv), __float_as_int(src), CTRL, RMASK, 0xF, false));
}

// ---------------- kernel 1: angle tables (once per call) ----------------
// tab floats: [0]=cos_local[2][1024], [2048]=sin_local[2][1024],
//             [4096]=cos_ent[2][512], [5120]=sin_ent[2][512]
__global__ void angles_kernel(const float* __restrict__ la,
                              const float* __restrict__ ea,
                              float* __restrict__ tab) {
    int t  = blockIdx.x * blockDim.x + threadIdx.x;
    int nt = gridDim.x * blockDim.x;
    for (int i = t; i < NLAYER * D_DIM; i += nt) {
        float s, c; sincosf(la[i], &s, &c);
        tab[i] = c; tab[2048 + i] = s;
    }
    for (int i = t; i < NLAYER * (D_DIM / 2); i += nt) {
        float s, c; sincosf(ea[i], &s, &c);
        tab[4096 + i] = c; tab[5120 + i] = s;
    }
}

// ---------------- kernel 2: main ----------------
__global__ __launch_bounds__(256) void qent_kernel(
        const float* __restrict__ x,
        const float* __restrict__ tab,
        float* __restrict__ out, int B)
{
    const int lane  = threadIdx.x & 63;
    const int wid   = threadIdx.x >> 6;
    const int gwave = blockIdx.x * WPB + wid;
    const int nwave = gridDim.x * WPB;

    __shared__ float4 tb[WPB][2][256];             // 32 KB: per-wave dbuf
    __shared__ float2 lds_ces[NLAYER][NPAIR][64];  // 8 KB: {cos,sin} packed

    // Ent coefficients -> LDS [L][m][lane] (lane-consecutive, conflict-free).
    for (int t = threadIdx.x; t < NLAYER * 512; t += 256) {
        int L = t >> 9, p = t & 511;
        int m = p >> 6, ln = p & 63;
        float2 cs;
        cs.x = tab[4096 + L * 512 + ln * 8 + m];
        cs.y = tab[5120 + L * 512 + ln * 8 + m];
        lds_ces[L][m][ln] = cs;
    }
    __syncthreads();

    // Local-rotation coefficients in registers (coalesced float4 loads).
    float cl[NLAYER][PER_LANE], sl[NLAYER][PER_LANE];
    #pragma unroll
    for (int L = 0; L < NLAYER; ++L) {
        const float4* cp = reinterpret_cast<const float4*>(tab + L * D_DIM + lane * PER_LANE);
        const float4* sp = reinterpret_cast<const float4*>(tab + 2048 + L * D_DIM + lane * PER_LANE);
        #pragma unroll
        for (int q = 0; q < 4; ++q) {
            float4 c4 = cp[q], s4 = sp[q];
            cl[L][4*q+0] = c4.x; cl[L][4*q+1] = c4.y; cl[L][4*q+2] = c4.z; cl[L][4*q+3] = c4.w;
            sl[L][4*q+0] = s4.x; sl[L][4*q+1] = s4.y; sl[L][4*q+2] = s4.z; sl[L][4*q+3] = s4.w;
        }
    }

    // Direct-to-LDS stage, pre-swizzled global source: LDS chunk q*64+l
    // receives global chunk q*64 + (l ^ (l>>3))  =>  LDS image is swz'd.
    const int l2 = lane ^ (lane >> 3);
    auto stage = [&](int b, int row) {
        const float* src = x + (size_t)row * D_DIM;
        #pragma unroll
        for (int q = 0; q < 4; ++q) {
            __builtin_amdgcn_global_load_lds(
                (const __attribute__((address_space(1))) void*)(src + q * 256 + l2 * 4),
                (__attribute__((address_space(3))) void*)&tb[wid][b][q * 64],
                16, 0, 0);
        }
    };

    stage(0, gwave);

    int it = 0;
    for (int row = gwave; row < B; row += nwave, ++it) {
        const int cur  = it & 1;
        const int nrow = row + nwave;

        // Counted prefetch wait. Steady state outstanding at this point:
        // [stage(cur) 4][stores(prev row) 4][stage(next) 4] -> vmcnt(8)
        // retires exactly stage(cur), leaves stores+next in flight.
        // First iteration has no stores: vmcnt(4). Last: drain all.
        if (nrow < B) {
            stage(cur ^ 1, nrow);
            if (it == 0) asm volatile("s_waitcnt vmcnt(4)" ::: "memory");
            else         asm volatile("s_waitcnt vmcnt(8)" ::: "memory");
        } else {
            asm volatile("s_waitcnt vmcnt(0)" ::: "memory");
        }

        // ---- segment read: lane l owns columns [16l, 16l+16) ----
        float v[PER_LANE];
        #pragma unroll
        for (int r = 0; r < 4; ++r) {
            float4 t = tb[wid][cur][swz(4 * lane + r)];
            v[4*r+0] = t.x; v[4*r+1] = t.y; v[4*r+2] = t.z; v[4*r+3] = t.w;
        }

        #pragma unroll
        for (int L = 0; L < NLAYER; ++L) {
            // ---------- local chain: u_{i+1} = s_i u_i + c_i v_{i+1} ----------
            float vnf = __shfl_down(v[0], 1);  // lane l+1's ORIGINAL v[0]

            // pass 1: this lane's composed affine map (A, B)
            float A = 1.f, Bv = 0.f;
            #pragma unroll
            for (int k = 0; k < PER_LANE; ++k) {
                float vn = (k < PER_LANE - 1) ? v[k + 1] : vnf;
                Bv = sl[L][k] * Bv + cl[L][k] * vn;
                A  = sl[L][k] * A;
            }

            // inclusive affine scan across 64 lanes, DPP (VALU) pipe:
            // row_shr 1,2,4,8 then row_bcast15 (rows 1,3), row_bcast31 (rows 2,3).
            // update_dpp's old-operand supplies the identity (A=1,B=0) for
            // invalid/masked lanes -> no predication needed.
            float Ai = A, Bi = Bv;
            #define SCAN_STEP(CTRL, RMASK) do {                   \
                float Au = dpp_mov<CTRL, RMASK>(Ai, 1.0f);        \
                float Bu = dpp_mov<CTRL, RMASK>(Bi, 0.0f);        \
                Bi = fmaf(Ai, Bu, Bi);                            \
                Ai *= Au; } while (0)
            SCAN_STEP(0x111, 0xF);   // row_shr:1
            SCAN_STEP(0x112, 0xF);   // row_shr:2
            SCAN_STEP(0x114, 0xF);   // row_shr:4
            SCAN_STEP(0x118, 0xF);   // row_shr:8
            SCAN_STEP(0x142, 0xA);   // row_bcast:15 -> rows 1,3
            SCAN_STEP(0x143, 0xC);   // row_bcast:31 -> rows 2,3
            #undef SCAN_STEP

            // exclusive shift by one lane (cross-row: bpermute)
            float Ax  = __shfl_up(Ai, 1);
            float Bx  = __shfl_up(Bi, 1);
            float v0b = __int_as_float(
                __builtin_amdgcn_readfirstlane(__float_as_int(v[0])));
            float u   = (lane == 0) ? v[0] : fmaf(Ax, v0b, Bx);

            // replay: finals f_i = c_i u_i - s_i v_{i+1}
            #pragma unroll
            for (int k = 0; k < PER_LANE - 1; ++k) {
                float vn = v[k + 1];
                float f  = cl[L][k] * u - sl[L][k] * vn;
                u        = sl[L][k] * u + cl[L][k] * vn;
                v[k] = f;
            }
            // wrap step i = D-1 uses a0 = provisional f_0 (lane 0)
            float a0 = __int_as_float(
                __builtin_amdgcn_readfirstlane(__float_as_int(v[0])));
            float vn15 = (lane == 63) ? a0 : vnf;
            float f15  = cl[L][PER_LANE-1] * u - sl[L][PER_LANE-1] * vn15;
            float un   = sl[L][PER_LANE-1] * u + cl[L][PER_LANE-1] * vn15;
            v[PER_LANE-1] = f15;
            float f0new = __int_as_float(
                __builtin_amdgcn_readlane(__float_as_int(un), 63));
            v[0] = (lane == 0) ? f0new : v[0];

            // ---------- ent layer: disjoint pairs, lane-local ----------
            #pragma unroll
            for (int m = 0; m < NPAIR; ++m) {
                float2 cs = lds_ces[L][m][lane];
                float x0 = v[2*m], x1 = v[2*m+1];
                v[2*m]   = cs.x * x0 - cs.y * x1;
                v[2*m+1] = cs.y * x0 + cs.x * x1;
            }
        }

        // ---- segment write back (swizzled), then coalesced store ----
        #pragma unroll
        for (int r = 0; r < 4; ++r) {
            float4 t;
            t.x = v[4*r+0]; t.y = v[4*r+1]; t.z = v[4*r+2]; t.w = v[4*r+3];
            tb[wid][cur][swz(4 * lane + r)] = t;
        }
        float4* op = reinterpret_cast<float4*>(out + (size_t)row * D_DIM);
        #pragma unroll
        for (int q = 0; q < 4; ++q) {
            float4 t = tb[wid][cur][swz(q * 64 + lane)];
            op[q * 64 + lane] = t;
        }
    }
}

extern "C" void kernel_launch(void* const* d_in, const int* in_sizes, int n_in,
                              void* d_out, int out_size, void* d_ws, size_t ws_size,
                              hipStream_t stream) {
    const float* x  = (const float*)d_in[0];
    const float* la = (const float*)d_in[1];
    const float* ea = (const float*)d_in[2];
    float* out = (float*)d_out;
    float* tab = (float*)d_ws;               // 6144 floats = 24 KB
    int B = in_sizes[0] / D_DIM;             // 32768

    angles_kernel<<<8, 256, 0, stream>>>(la, ea, tab);
    // 1024 blocks x 4 waves, 8 rows/wave: 7/8 iterations fully prefetched.
    qent_kernel<<<1024, 256, 0, stream>>>(x, tab, out, B);
}

// Round 8
// 54.708 us; speedup vs baseline: 3.7366x; 1.0561x over previous
//
#include <hip/hip_runtime.h>

#define D_DIM    1024
#define PER_LANE 16   // D / 64
#define NLAYER   2
#define NPAIR    8    // ent pairs per lane
#define WPB      4    // waves per block (blockDim = 256)

// Native 4-float vector for nontemporal builtins (HIP float4 class rejected).
typedef float nf4 __attribute__((ext_vector_type(4)));

// XOR swizzle over 16B chunk index: bijective involution; makes the coalesced
// phase (chunks q*64+l) and the segment phase (chunks 4l+r) bank-uniform.
__device__ __forceinline__ int swz(int c) { return c ^ ((c >> 3) & 7); }

// DPP move with explicit old-value for invalid/masked lanes.
// Empirical convention (validated R6): row_shr:d  => lane i <- lane i-d.
// Hence wave_shr:1 (0x138) = shfl_up(1); wave_shl:1 (0x130) = shfl_down(1).
template<int CTRL, int RMASK>
__device__ __forceinline__ float dpp_mov(float src, float oldv) {
    return __int_as_float(__builtin_amdgcn_update_dpp(
        __float_as_int(oldv), __float_as_int(src), CTRL, RMASK, 0xF, false));
}

// ---------------- kernel 1: angle tables (once per call) ----------------
// tab floats: [0]=cos_local[2][1024], [2048]=sin_local[2][1024],
//             [4096]=cos_ent[2][512], [5120]=sin_ent[2][512]
__global__ void angles_kernel(const float* __restrict__ la,
                              const float* __restrict__ ea,
                              float* __restrict__ tab) {
    int t  = blockIdx.x * blockDim.x + threadIdx.x;
    int nt = gridDim.x * blockDim.x;
    for (int i = t; i < NLAYER * D_DIM; i += nt) {
        float s, c; sincosf(la[i], &s, &c);
        tab[i] = c; tab[2048 + i] = s;
    }
    for (int i = t; i < NLAYER * (D_DIM / 2); i += nt) {
        float s, c; sincosf(ea[i], &s, &c);
        tab[4096 + i] = c; tab[5120 + i] = s;
    }
}

// ---------------- kernel 2: main ----------------
__global__ __launch_bounds__(256) void qent_kernel(
        const float* __restrict__ x,
        const float* __restrict__ tab,
        float* __restrict__ out, int B)
{
    const int lane  = threadIdx.x & 63;
    const int wid   = threadIdx.x >> 6;
    const int gwave = blockIdx.x * WPB + wid;
    const int nwave = gridDim.x * WPB;

    __shared__ float4 tb[WPB][2][256];             // 32 KB: per-wave dbuf
    __shared__ float2 lds_ces[NLAYER][NPAIR][64];  // 8 KB: {cos,sin} packed

    // Ent coefficients -> LDS [L][m][lane] (lane-consecutive, conflict-free).
    for (int t = threadIdx.x; t < NLAYER * 512; t += 256) {
        int L = t >> 9, p = t & 511;
        int m = p >> 6, ln = p & 63;
        float2 cs;
        cs.x = tab[4096 + L * 512 + ln * 8 + m];
        cs.y = tab[5120 + L * 512 + ln * 8 + m];
        lds_ces[L][m][ln] = cs;
    }
    __syncthreads();

    // Local-rotation coefficients in registers (coalesced float4 loads).
    float cl[NLAYER][PER_LANE], sl[NLAYER][PER_LANE];
    #pragma unroll
    for (int L = 0; L < NLAYER; ++L) {
        const float4* cp = reinterpret_cast<const float4*>(tab + L * D_DIM + lane * PER_LANE);
        const float4* sp = reinterpret_cast<const float4*>(tab + 2048 + L * D_DIM + lane * PER_LANE);
        #pragma unroll
        for (int q = 0; q < 4; ++q) {
            float4 c4 = cp[q], s4 = sp[q];
            cl[L][4*q+0] = c4.x; cl[L][4*q+1] = c4.y; cl[L][4*q+2] = c4.z; cl[L][4*q+3] = c4.w;
            sl[L][4*q+0] = s4.x; sl[L][4*q+1] = s4.y; sl[L][4*q+2] = s4.z; sl[L][4*q+3] = s4.w;
        }
    }

    // Direct-to-LDS stage, pre-swizzled global source: LDS chunk q*64+l
    // receives global chunk q*64 + (l ^ (l>>3))  =>  LDS image is swz'd.
    const int l2 = lane ^ (lane >> 3);
    auto stage = [&](int b, int row) {
        const float* src = x + (size_t)row * D_DIM;
        #pragma unroll
        for (int q = 0; q < 4; ++q) {
            __builtin_amdgcn_global_load_lds(
                (const __attribute__((address_space(1))) void*)(src + q * 256 + l2 * 4),
                (__attribute__((address_space(3))) void*)&tb[wid][b][q * 64],
                16, 0, 0);
        }
    };

    stage(0, gwave);

    int it = 0;
    for (int row = gwave; row < B; row += nwave, ++it) {
        const int cur  = it & 1;
        const int nrow = row + nwave;

        // Counted prefetch wait. Steady state outstanding at this point:
        // [stage(cur) 4][stores(prev row) 4][stage(next) 4] -> vmcnt(8)
        // retires exactly stage(cur), leaves stores+next in flight.
        if (nrow < B) {
            stage(cur ^ 1, nrow);
            if (it == 0) asm volatile("s_waitcnt vmcnt(4)" ::: "memory");
            else         asm volatile("s_waitcnt vmcnt(8)" ::: "memory");
        } else {
            asm volatile("s_waitcnt vmcnt(0)" ::: "memory");
        }

        // ---- segment read: lane l owns columns [16l, 16l+16) ----
        float v[PER_LANE];
        #pragma unroll
        for (int r = 0; r < 4; ++r) {
            float4 t = tb[wid][cur][swz(4 * lane + r)];
            v[4*r+0] = t.x; v[4*r+1] = t.y; v[4*r+2] = t.z; v[4*r+3] = t.w;
        }

        #pragma unroll
        for (int L = 0; L < NLAYER; ++L) {
            // ---------- local chain: u_{i+1} = s_i u_i + c_i v_{i+1} ----------
            // vnf = lane l+1's ORIGINAL v[0]  (shfl_down 1 == wave_shl:1)
            float vnf = dpp_mov<0x130, 0xF>(v[0], v[0]);

            // pass 1: this lane's composed affine map (A, B)
            float A = 1.f, Bv = 0.f;
            #pragma unroll
            for (int k = 0; k < PER_LANE; ++k) {
                float vn = (k < PER_LANE - 1) ? v[k + 1] : vnf;
                Bv = sl[L][k] * Bv + cl[L][k] * vn;
                A  = sl[L][k] * A;
            }

            // inclusive affine scan across 64 lanes, all-DPP (VALU pipe).
            float Ai = A, Bi = Bv;
            #define SCAN_STEP(CTRL, RMASK) do {                   \
                float Au = dpp_mov<CTRL, RMASK>(Ai, 1.0f);        \
                float Bu = dpp_mov<CTRL, RMASK>(Bi, 0.0f);        \
                Bi = fmaf(Ai, Bu, Bi);                            \
                Ai *= Au; } while (0)
            SCAN_STEP(0x111, 0xF);   // row_shr:1
            SCAN_STEP(0x112, 0xF);   // row_shr:2
            SCAN_STEP(0x114, 0xF);   // row_shr:4
            SCAN_STEP(0x118, 0xF);   // row_shr:8
            SCAN_STEP(0x142, 0xA);   // row_bcast:15 -> rows 1,3
            SCAN_STEP(0x143, 0xC);   // row_bcast:31 -> rows 2,3
            #undef SCAN_STEP

            // exclusive shift by one lane (shfl_up 1 == wave_shr:1)
            float Ax = dpp_mov<0x138, 0xF>(Ai, 0.0f);
            float Bx = dpp_mov<0x138, 0xF>(Bi, 0.0f);
            float v0b = __int_as_float(
                __builtin_amdgcn_readfirstlane(__float_as_int(v[0])));
            float u   = (lane == 0) ? v[0] : fmaf(Ax, v0b, Bx);

            // replay: finals f_i = c_i u_i - s_i v_{i+1}
            #pragma unroll
            for (int k = 0; k < PER_LANE - 1; ++k) {
                float vn = v[k + 1];
                float f  = cl[L][k] * u - sl[L][k] * vn;
                u        = sl[L][k] * u + cl[L][k] * vn;
                v[k] = f;
            }
            // wrap step i = D-1 uses a0 = provisional f_0 (lane 0)
            float a0 = __int_as_float(
                __builtin_amdgcn_readfirstlane(__float_as_int(v[0])));
            float vn15 = (lane == 63) ? a0 : vnf;
            float f15  = cl[L][PER_LANE-1] * u - sl[L][PER_LANE-1] * vn15;
            float un   = sl[L][PER_LANE-1] * u + cl[L][PER_LANE-1] * vn15;
            v[PER_LANE-1] = f15;
            float f0new = __int_as_float(
                __builtin_amdgcn_readlane(__float_as_int(un), 63));
            v[0] = (lane == 0) ? f0new : v[0];

            // ---------- ent layer: disjoint pairs, lane-local ----------
            #pragma unroll
            for (int m = 0; m < NPAIR; ++m) {
                float2 cs = lds_ces[L][m][lane];
                float x0 = v[2*m], x1 = v[2*m+1];
                v[2*m]   = cs.x * x0 - cs.y * x1;
                v[2*m+1] = cs.y * x0 + cs.x * x1;
            }
        }

        // ---- segment write back (swizzled), then coalesced nt-store ----
        #pragma unroll
        for (int r = 0; r < 4; ++r) {
            float4 t;
            t.x = v[4*r+0]; t.y = v[4*r+1]; t.z = v[4*r+2]; t.w = v[4*r+3];
            tb[wid][cur][swz(4 * lane + r)] = t;
        }
        nf4* op = reinterpret_cast<nf4*>(out + (size_t)row * D_DIM);
        #pragma unroll
        for (int q = 0; q < 4; ++q) {
            float4 t = tb[wid][cur][swz(q * 64 + lane)];
            nf4 w; w.x = t.x; w.y = t.y; w.z = t.z; w.w = t.w;
            // Nontemporal: don't let output allocate in L2/L3 -> input stays
            // Infinity-Cache-resident across graph replays.
            __builtin_nontemporal_store(w, &op[q * 64 + lane]);
        }
    }
}

extern "C" void kernel_launch(void* const* d_in, const int* in_sizes, int n_in,
                              void* d_out, int out_size, void* d_ws, size_t ws_size,
                              hipStream_t stream) {
    const float* x  = (const float*)d_in[0];
    const float* la = (const float*)d_in[1];
    const float* ea = (const float*)d_in[2];
    float* out = (float*)d_out;
    float* tab = (float*)d_ws;               // 6144 floats = 24 KB
    int B = in_sizes[0] / D_DIM;             // 32768

    angles_kernel<<<64, 256, 0, stream>>>(la, ea, tab);
    // 1024 blocks x 4 waves, 8 rows/wave: 7/8 iterations fully prefetched.
    qent_kernel<<<1024, 256, 0, stream>>>(x, tab, out, B);
}